// Round 1
// baseline (269.789 us; speedup 1.0000x reference)
//
#include <hip/hip_runtime.h>

#define NB 16
#define NC 64
#define C2 32
#define C4 16
#define HH 256
#define WW 256
#define HW (HH*WW)          // 65536
#define NPIX (NB*NC*HW)

// ws layout (floats):
//   [0, 2048)        w1T   : w1T[c*32+o] = w1[o*64+c]
//   [2048, 10240)    S1    : [b][o32][s16]   (per-b stride 512)
//   [10240, 18432)   S2
//   [18432, 26624)   S3
//   [26624, 30720)   gates : [b][o16][s16]   (per-b stride 256)

__global__ __launch_bounds__(256) void prep_kernel(const float* __restrict__ w1,
                                                   float* __restrict__ ws) {
    int t = threadIdx.x;
    for (int i = t; i < 24576; i += 256) ws[2048 + i] = 0.f;
    for (int i = t; i < 2048; i += 256) {
        int o = i >> 6, c = i & 63;
        ws[c * 32 + o] = w1[i];
    }
}

// Stats: S1,S2,S3 per (b, o in [0,32), s in [0,16)) over the 4096 spatial blocks.
// Each CUDA block handles rows h == r (mod 4) only -> every thread has a fixed s.
__global__ __launch_bounds__(256) void stats_kernel(const float* __restrict__ x,
                                                    const float* __restrict__ w1t,
                                                    const float* __restrict__ b1,
                                                    float* __restrict__ stats) {
    int b     = blockIdx.x >> 6;   // 64 blocks per batch
    int sub   = blockIdx.x & 63;
    int r     = sub & 3;           // h residue
    int chunk = sub >> 2;          // 16 chunks of 4 rows each
    int w     = threadIdx.x;       // 0..255 -> column
    const float* xb = x + (size_t)b * NC * HW;

    float S1[32], S2[32], S3[32];
    #pragma unroll
    for (int o = 0; o < 32; o++) { S1[o] = 0.f; S2[o] = 0.f; S3[o] = 0.f; }

    for (int i = 0; i < 4; ++i) {
        int h = r + 4 * (chunk * 4 + i);
        const float* xp = xb + h * WW + w;
        float acc[32];
        #pragma unroll
        for (int o = 0; o < 32; o++) acc[o] = b1[o];
        #pragma unroll 8
        for (int c = 0; c < 64; c++) {
            float xc = xp[(size_t)c * HW];
            #pragma unroll
            for (int o = 0; o < 32; o++) acc[o] += w1t[c * 32 + o] * xc;
        }
        #pragma unroll
        for (int o = 0; o < 32; o++) {
            float v = acc[o] > 0.f ? acc[o] : 0.f;
            S1[o] += v;
            float p = v * v;
            S2[o] += p;
            S3[o] += p * v;
        }
    }

    // Reduce over the 16 lanes sharing (lane & 3) within each wave (xor 4,8,16,32),
    // then lanes 0..3 of each wave atomically add to global.
    int lane = threadIdx.x & 63;
    #pragma unroll
    for (int o = 0; o < 32; o++) {
        float a = S1[o], bb = S2[o], cc = S3[o];
        #pragma unroll
        for (int m = 4; m <= 32; m <<= 1) {
            a  += __shfl_xor(a,  m);
            bb += __shfl_xor(bb, m);
            cc += __shfl_xor(cc, m);
        }
        if (lane < 4) {
            int si = r * 4 + lane;
            int idx = b * 512 + o * 16 + si;
            atomicAdd(&stats[idx],         a);
            atomicAdd(&stats[8192 + idx],  bb);
            atomicAdd(&stats[16384 + idx], cc);
        }
    }
}

// Tiny attention: qkv = mean + m3; softmax(q q^T) @ v; gate = sigmoid(y).
__global__ __launch_bounds__(512) void attn_kernel(const float* __restrict__ stats,
                                                   float* __restrict__ gates) {
    int b = blockIdx.x;
    int t = threadIdx.x;
    __shared__ float qkv[512];
    {
        int idx = b * 512 + t;
        float S1 = stats[idx];
        float S2 = stats[8192 + idx];
        float S3 = stats[16384 + idx];
        float mu = S1 * (1.f / 4096.f);
        // sum (x-mu)^3 = S3 - 3 mu S2 + 2 N mu^3 ; m3 = that / 16
        float m3 = (S3 - 3.f * mu * S2 + 2.f * 4096.f * mu * mu * mu) * (1.f / 16.f);
        qkv[t] = mu + m3;
    }
    __syncthreads();
    if (t < 256) {
        int o = t >> 4, s = t & 15;
        float qs = qkv[o * 16 + s];
        float mx = -1e30f;
        #pragma unroll
        for (int k = 0; k < 16; k++) mx = fmaxf(mx, qs * qkv[o * 16 + k]);
        float sum = 0.f, y = 0.f;
        #pragma unroll
        for (int k = 0; k < 16; k++) {
            float e = __expf(qs * qkv[o * 16 + k] - mx);
            sum += e;
            y   += e * qkv[(16 + o) * 16 + k];
        }
        y /= sum;
        float g = 1.f / (1.f + __expf(-y));
        gates[b * 256 + o * 16 + s] = g;
    }
}

// Per-pixel: recompute vx channels, gate, 16->64 conv, + bias + residual.
__global__ __launch_bounds__(256) void out_kernel(const float* __restrict__ x,
                                                  const float* __restrict__ w1t,
                                                  const float* __restrict__ b1,
                                                  const float* __restrict__ w2,
                                                  const float* __restrict__ b2,
                                                  const float* __restrict__ gates,
                                                  float* __restrict__ out) {
    int bh = blockIdx.x;
    int b  = bh >> 8;      // 256 rows per batch
    int h  = bh & 255;
    int w  = threadIdx.x;  // 0..255
    int s  = (h & 3) * 4 + (w & 3);
    const float* xb = x   + (size_t)b * NC * HW + h * WW + w;
    float*       ob = out + (size_t)b * NC * HW + h * WW + w;

    __shared__ float gsh[256];
    gsh[w] = gates[b * 256 + w];
    __syncthreads();

    float xr[64];
    #pragma unroll
    for (int c = 0; c < 64; c++) xr[c] = xb[(size_t)c * HW];

    float fv[16];
    #pragma unroll
    for (int j = 0; j < 16; j++) fv[j] = b1[16 + j];
    #pragma unroll
    for (int c = 0; c < 64; c++) {
        float xc = xr[c];
        #pragma unroll
        for (int j = 0; j < 16; j++) fv[j] += w1t[c * 32 + 16 + j] * xc;
    }
    #pragma unroll
    for (int j = 0; j < 16; j++) {
        float v = fv[j] > 0.f ? fv[j] : 0.f;
        fv[j] = v * gsh[j * 16 + s];
    }
    #pragma unroll
    for (int o = 0; o < 64; o++) {
        float r = b2[o] + xr[o];
        #pragma unroll
        for (int j = 0; j < 16; j++) r += w2[o * 16 + j] * fv[j];
        ob[(size_t)o * HW] = r;
    }
}

extern "C" void kernel_launch(void* const* d_in, const int* in_sizes, int n_in,
                              void* d_out, int out_size, void* d_ws, size_t ws_size,
                              hipStream_t stream) {
    const float* x  = (const float*)d_in[0];
    const float* w1 = (const float*)d_in[1];
    const float* b1 = (const float*)d_in[2];
    const float* w2 = (const float*)d_in[3];
    const float* b2 = (const float*)d_in[4];
    float* ws    = (float*)d_ws;
    float* w1t   = ws;
    float* stats = ws + 2048;
    float* gates = ws + 26624;
    float* out   = (float*)d_out;

    prep_kernel <<<1,    256, 0, stream>>>(w1, ws);
    stats_kernel<<<1024, 256, 0, stream>>>(x, w1t, b1, stats);
    attn_kernel <<<16,   512, 0, stream>>>(stats, gates);
    out_kernel  <<<4096, 256, 0, stream>>>(x, w1t, b1, w2, b2, gates, out);
}